// Round 22
// baseline (454.652 us; speedup 1.0000x reference)
//
#include <hip/hip_runtime.h>
#include <hip/hip_bf16.h>
#include <math.h>

// Problem constants
#define NB 2
#define NT 2048
#define NTOK 4096      // NB*NT
#define DD 1024
#define FF 4096
#define NE 8
#define KSEL 2
#define BM 128
#define BN 128
#define BK 32          // K-step (double-buffered)
#define ROWCAP 9216    // 72 tiles * 128
#define ROWTILES 72
#define KP2 2          // split-K factor for GEMM2
#define BSTR 34        // B LDS row stride in shorts (17 dwords: odd -> conflict-free reads)

typedef __attribute__((ext_vector_type(8))) short short8_t;
typedef __attribute__((ext_vector_type(4))) float f32x4;

__device__ __forceinline__ unsigned short f2bf(float f){
  unsigned u = __float_as_uint(f);
  unsigned r = (u + 0x7fffu + ((u >> 16) & 1u)) >> 16;
  return (unsigned short)r;
}

// pack two f32 -> (bf16(a) | bf16(b)<<16), round-half-up (margin-safe vs RNE)
__device__ __forceinline__ unsigned pk2(float a, float b){
  return ((__float_as_uint(a) + 0x8000u) >> 16) | ((__float_as_uint(b) + 0x8000u) & 0xffff0000u);
}

// bijective XCD-chunked swizzle (m204)
__device__ __forceinline__ int xcd_swz(int lin, int nwg){
  int q = nwg >> 3, r = nwg & 7;
  int xcd = lin & 7, idx = lin >> 3;
  return (xcd < r ? xcd * (q + 1) : r * (q + 1) + (xcd - r) * q) + idx;
}

#define GLOAD_LDS(g, l) \
  __builtin_amdgcn_global_load_lds((const __attribute__((address_space(1))) void*)(g), \
                                   (__attribute__((address_space(3))) void*)(l), 16, 0, 0)
#define VMCNT0 asm volatile("s_waitcnt vmcnt(0)" ::: "memory")
#define LGKM0  asm volatile("s_waitcnt lgkmcnt(0)" ::: "memory")
#define RAWBAR __builtin_amdgcn_s_barrier()

// ---------------- prep: convert x -> bf16, gating logits + top2 ----------------

__global__ void k_prep(const float* __restrict__ x, const float* __restrict__ wg,
                       short* __restrict__ xb, int* __restrict__ topk_idx,
                       float* __restrict__ topk_gate, int* __restrict__ counts){
  int wid = threadIdx.x >> 6, lane = threadIdx.x & 63;
  int t = blockIdx.x * 4 + wid;
  const float* xr = x + (size_t)t * DD;
  short* xbr = xb + (size_t)t * DD;
  double acc[NE];
#pragma unroll
  for (int e = 0; e < NE; ++e) acc[e] = 0.0;
#pragma unroll
  for (int p = 0; p < 4; ++p){
    int d = p * 256 + lane * 4;
    float4 v = *(const float4*)(xr + d);
    short4 o;
    o.x = (short)f2bf(v.x); o.y = (short)f2bf(v.y);
    o.z = (short)f2bf(v.z); o.w = (short)f2bf(v.w);
    *(short4*)(xbr + d) = o;
    const float* w0 = wg + (size_t)d * NE;
    float vv[4] = {v.x, v.y, v.z, v.w};
#pragma unroll
    for (int j = 0; j < 4; ++j){
      double xv = (double)vv[j];
#pragma unroll
      for (int e = 0; e < NE; ++e) acc[e] += xv * (double)w0[j * NE + e];
    }
  }
#pragma unroll
  for (int e = 0; e < NE; ++e){
#pragma unroll
    for (int s = 32; s; s >>= 1) acc[e] += __shfl_xor(acc[e], s, 64);
  }
  if (lane == 0){
    int i0 = 0; double v0 = acc[0];
#pragma unroll
    for (int e = 1; e < NE; ++e) if (acc[e] > v0){ v0 = acc[e]; i0 = e; }
    int i1 = -1; double v1 = -1e300;
#pragma unroll
    for (int e = 0; e < NE; ++e) if (e != i0 && acc[e] > v1){ v1 = acc[e]; i1 = e; }
    double g0 = 1.0 / (1.0 + exp(v1 - v0));
    topk_idx[2 * t] = i0; topk_idx[2 * t + 1] = i1;
    topk_gate[2 * t] = (float)g0; topk_gate[2 * t + 1] = (float)(1.0 - g0);
    atomicAdd(&counts[i0], 1);
    atomicAdd(&counts[i1], 1);
  }
}

// ---------------- routing (single block) ----------------

__global__ void k_route_all(const int* __restrict__ counts, const int* __restrict__ topk_idx,
                            const float* __restrict__ topk_gate, int* __restrict__ poff_g,
                            int* __restrict__ row_token, float* __restrict__ row_gate,
                            int* __restrict__ slot_of){
  __shared__ int poff[NE + 1], cur[NE], rends[NE];
  if (threadIdx.x == 0){
    int off = 0;
    for (int e = 0; e < NE; ++e){
      poff[e] = off; cur[e] = off; rends[e] = off + counts[e];
      off += (counts[e] + BM - 1) & ~(BM - 1);
    }
    poff[NE] = off;
    for (int e = 0; e <= NE; ++e) poff_g[e] = poff[e];
  }
  __syncthreads();
  for (int t = threadIdx.x; t < NTOK; t += 256){
#pragma unroll
    for (int k = 0; k < KSEL; ++k){
      int e = topk_idx[2 * t + k];
      float g = topk_gate[2 * t + k];
      int slot = atomicAdd(&cur[e], 1);
      row_token[slot] = t;
      row_gate[slot] = g;
      slot_of[2 * t + k] = slot;
    }
  }
  __syncthreads();
#pragma unroll
  for (int e = 0; e < NE; ++e)
    for (int s = rends[e] + (int)threadIdx.x; s < poff[e + 1]; s += 256){
      row_token[s] = 0; row_gate[s] = 0.f;
    }
}

// ---------------- GEMM1: h = gelu(X_gather @ W1[e] + b1[e]) ----------------
// NO pre-transposed weights: B staged from f32 W1 [e][k=d][n=f] directly:
// per thread 2 k-rows x 8 n (4x float4) -> pack k-pairs bf16 -> 8 b32 LDS writes
// into [n][BSTR] layout; B-frags read as 4x b32 (conflict-free, odd dword stride).

__launch_bounds__(256, 4)
__global__ void k_gemm1(const short* __restrict__ xb, const float* __restrict__ W1,
                        const float* __restrict__ b1, short* __restrict__ h,
                        const int* __restrict__ row_token, const int* __restrict__ poff){
  __shared__ short As[2][BM * BK];     // 2 x 8 KB
  __shared__ short Bs[2][BN * BSTR];   // 2 x 8704 B
  int wg = xcd_swz(blockIdx.x, ROWTILES * (FF / BN));
  int g = wg >> 6, t6 = wg & 63;
  int bx = (g >> 2) * 8 + (t6 & 7);
  int by = (g & 3) * 8 + (t6 >> 3);
  int row0 = bx * BM;
  if (row0 >= poff[NE]) return;
  int e = 0;
  while (row0 >= poff[e + 1]) ++e;
  int n0 = by * BN;
  int tid = threadIdx.x;

  // A staging (unchanged r13/r18 path)
  const short* asrc[2];
#pragma unroll
  for (int p = 0; p < 2; ++p){
    int L = p * 256 + tid;
    int r = L >> 2, c = L & 3;
    int cd = c ^ ((r >> 1) & 3);
    int tok = row_token[row0 + r];
    asrc[p] = xb + (size_t)tok * DD + cd * 8;
  }
  // B staging source: thread -> (n-chunk nc of 8, k-pair kp)
  int nc = tid & 15, kp = tid >> 4;           // nc 0..15, kp 0..15 (k = 2kp)
  const float* bsrcf = W1 + (size_t)e * DD * FF + (size_t)(2 * kp) * FF + n0 + nc * 8;

  f32x4 acc[4][4];
#pragma unroll
  for (int i = 0; i < 4; ++i)
#pragma unroll
    for (int j = 0; j < 4; ++j) acc[i][j] = (f32x4){0.f, 0.f, 0.f, 0.f};

  int wid = tid >> 6, lane = tid & 63;
  int wr = wid >> 1, wc = wid & 1;
  int lrow = lane & 15, lk = lane >> 4;

  auto STAGE_A = [&](int nb, int k0){
#pragma unroll
    for (int p = 0; p < 2; ++p)
      GLOAD_LDS(asrc[p] + k0, &As[nb][0] + tid * 8 + p * 2048);
  };
  float4 rb0, rb1, rb2, rb3;
  auto LOADB = [&](int k0){
    const float* s = bsrcf + (size_t)k0 * FF;
    rb0 = *(const float4*)(s);
    rb1 = *(const float4*)(s + 4);
    rb2 = *(const float4*)(s + FF);
    rb3 = *(const float4*)(s + FF + 4);
  };
  auto PACKW = [&](int nb){
    int* Bw = (int*)(&Bs[nb][0]);
    int n8 = nc * 8;
    Bw[(n8 + 0) * 17 + kp] = pk2(rb0.x, rb2.x);
    Bw[(n8 + 1) * 17 + kp] = pk2(rb0.y, rb2.y);
    Bw[(n8 + 2) * 17 + kp] = pk2(rb0.z, rb2.z);
    Bw[(n8 + 3) * 17 + kp] = pk2(rb0.w, rb2.w);
    Bw[(n8 + 4) * 17 + kp] = pk2(rb1.x, rb3.x);
    Bw[(n8 + 5) * 17 + kp] = pk2(rb1.y, rb3.y);
    Bw[(n8 + 6) * 17 + kp] = pk2(rb1.z, rb3.z);
    Bw[(n8 + 7) * 17 + kp] = pk2(rb1.w, rb3.w);
  };

  // prologue: tile 0 -> buf 0
  LOADB(0);
  STAGE_A(0, 0);
  VMCNT0;
  PACKW(0);
  LGKM0; RAWBAR;

  const int NKT = DD / BK;   // 32
#pragma unroll 1
  for (int kt = 0; kt < NKT; ++kt){
    int b = kt & 1;
    bool more = (kt + 1 < NKT);
    if (more){ LOADB((kt + 1) * BK); STAGE_A(b ^ 1, (kt + 1) * BK); }
    short8_t a[4], bb[4];
#pragma unroll
    for (int m = 0; m < 4; ++m){
      int r = wr * 64 + m * 16 + lrow;
      a[m] = *(const short8_t*)(&As[b][0] + r * BK + ((lk ^ ((r >> 1) & 3)) * 8));
    }
    const int* Bi = (const int*)(&Bs[b][0]);
#pragma unroll
    for (int n = 0; n < 4; ++n){
      int rn = wc * 64 + n * 16 + lrow;
      int bi = rn * 17 + lk * 4;
      int4 w4;
      w4.x = Bi[bi]; w4.y = Bi[bi + 1]; w4.z = Bi[bi + 2]; w4.w = Bi[bi + 3];
      bb[n] = *(short8_t*)&w4;
    }
#pragma unroll
    for (int m = 0; m < 4; ++m)
#pragma unroll
      for (int n = 0; n < 4; ++n)
        acc[m][n] = __builtin_amdgcn_mfma_f32_16x16x32_bf16(a[m], bb[n], acc[m][n], 0, 0, 0);
    if (more){ VMCNT0; PACKW(b ^ 1); }
    LGKM0; RAWBAR;
  }

  const float* b1e = b1 + (size_t)e * FF;
  float bias[4];
#pragma unroll
  for (int n = 0; n < 4; ++n) bias[n] = b1e[n0 + wc * 64 + n * 16 + lrow];
#pragma unroll
  for (int m = 0; m < 4; ++m){
#pragma unroll
    for (int j = 0; j < 4; ++j){
      int row = row0 + wr * 64 + m * 16 + lk * 4 + j;
      short* hr = h + (size_t)row * FF + n0 + wc * 64 + lrow;
#pragma unroll
      for (int n = 0; n < 4; ++n){
        float v = acc[m][n][j] + bias[n];
        float u = 0.7978845608028654f * (v + 0.044715f * v * v * v);
        float gl = v / (1.0f + __expf(-2.0f * u));   // = 0.5v(1+tanh(u))
        hr[n * 16] = (short)f2bf(gl);
      }
    }
  }
}

// ---------------- GEMM2 (split-K, non-atomic): same direct-W2 B staging ----------------

__launch_bounds__(256, 4)
__global__ void k_gemm2(const short* __restrict__ h, const float* __restrict__ W2,
                        const float* __restrict__ b2, float* __restrict__ ya,
                        float* __restrict__ yb, const int* __restrict__ poff){
  __shared__ short As[2][BM * BK];
  __shared__ short Bs[2][BN * BSTR];
  int wg = xcd_swz(blockIdx.x, ROWTILES * (DD / BN) * KP2);
  int kz = wg / (ROWTILES * (DD / BN));
  int c5 = wg % (ROWTILES * (DD / BN));
  int g = c5 >> 5, t5 = c5 & 31;
  int bx = g * 4 + (t5 & 3);
  int by = t5 >> 2;
  int row0 = bx * BM;
  if (row0 >= poff[NE]) return;
  int e = 0;
  while (row0 >= poff[e + 1]) ++e;
  int n0 = by * BN;
  int tid = threadIdx.x;
  int kbeg = kz * (FF / KP2);   // k offset (k = f dim)

  const short* asrc[2];
#pragma unroll
  for (int p = 0; p < 2; ++p){
    int L = p * 256 + tid;
    int r = L >> 2, c = L & 3;
    int cd = c ^ ((r >> 1) & 3);
    asrc[p] = h + (size_t)(row0 + r) * FF + kbeg + cd * 8;
  }
  int nc = tid & 15, kp = tid >> 4;
  const float* bsrcf = W2 + (size_t)e * FF * DD + (size_t)(kbeg + 2 * kp) * DD + n0 + nc * 8;

  f32x4 acc[4][4];
#pragma unroll
  for (int i = 0; i < 4; ++i)
#pragma unroll
    for (int j = 0; j < 4; ++j) acc[i][j] = (f32x4){0.f, 0.f, 0.f, 0.f};

  int wid = tid >> 6, lane = tid & 63;
  int wr = wid >> 1, wc = wid & 1;
  int lrow = lane & 15, lk = lane >> 4;

  auto STAGE_A = [&](int nb, int k0){
#pragma unroll
    for (int p = 0; p < 2; ++p)
      GLOAD_LDS(asrc[p] + k0, &As[nb][0] + tid * 8 + p * 2048);
  };
  float4 rb0, rb1, rb2, rb3;
  auto LOADB = [&](int k0){
    const float* s = bsrcf + (size_t)k0 * DD;
    rb0 = *(const float4*)(s);
    rb1 = *(const float4*)(s + 4);
    rb2 = *(const float4*)(s + DD);
    rb3 = *(const float4*)(s + DD + 4);
  };
  auto PACKW = [&](int nb){
    int* Bw = (int*)(&Bs[nb][0]);
    int n8 = nc * 8;
    Bw[(n8 + 0) * 17 + kp] = pk2(rb0.x, rb2.x);
    Bw[(n8 + 1) * 17 + kp] = pk2(rb0.y, rb2.y);
    Bw[(n8 + 2) * 17 + kp] = pk2(rb0.z, rb2.z);
    Bw[(n8 + 3) * 17 + kp] = pk2(rb0.w, rb2.w);
    Bw[(n8 + 4) * 17 + kp] = pk2(rb1.x, rb3.x);
    Bw[(n8 + 5) * 17 + kp] = pk2(rb1.y, rb3.y);
    Bw[(n8 + 6) * 17 + kp] = pk2(rb1.z, rb3.z);
    Bw[(n8 + 7) * 17 + kp] = pk2(rb1.w, rb3.w);
  };

  LOADB(0);
  STAGE_A(0, 0);
  VMCNT0;
  PACKW(0);
  LGKM0; RAWBAR;

  const int NKT = (FF / KP2) / BK;   // 64
#pragma unroll 1
  for (int kt = 0; kt < NKT; ++kt){
    int b = kt & 1;
    bool more = (kt + 1 < NKT);
    if (more){ LOADB((kt + 1) * BK); STAGE_A(b ^ 1, (kt + 1) * BK); }
    short8_t a[4], bb[4];
#pragma unroll
    for (int m = 0; m < 4; ++m){
      int r = wr * 64 + m * 16 + lrow;
      a[m] = *(const short8_t*)(&As[b][0] + r * BK + ((lk ^ ((r >> 1) & 3)) * 8));
    }
    const int* Bi = (const int*)(&Bs[b][0]);
#pragma unroll
    for (int n = 0; n < 4; ++n){
      int rn = wc * 64 + n * 16 + lrow;
      int bi = rn * 17 + lk * 4;
      int4 w4;
      w4.x = Bi[bi]; w4.y = Bi[bi + 1]; w4.z = Bi[bi + 2]; w4.w = Bi[bi + 3];
      bb[n] = *(short8_t*)&w4;
    }
#pragma unroll
    for (int m = 0; m < 4; ++m)
#pragma unroll
      for (int n = 0; n < 4; ++n)
        acc[m][n] = __builtin_amdgcn_mfma_f32_16x16x32_bf16(a[m], bb[n], acc[m][n], 0, 0, 0);
    if (more){ VMCNT0; PACKW(b ^ 1); }
    LGKM0; RAWBAR;
  }

  float* y = (kz == 0) ? ya : yb;
  const float* b2e = b2 + (size_t)e * DD;
  float bias[4];
#pragma unroll
  for (int n = 0; n < 4; ++n) bias[n] = (kz == 0) ? b2e[n0 + wc * 64 + n * 16 + lrow] : 0.0f;
#pragma unroll
  for (int m = 0; m < 4; ++m){
#pragma unroll
    for (int j = 0; j < 4; ++j){
      int row = row0 + wr * 64 + m * 16 + lk * 4 + j;
      float* yr = y + (size_t)row * DD + n0 + wc * 64 + lrow;
#pragma unroll
      for (int n = 0; n < 4; ++n)
        yr[n * 16] = acc[m][n][j] + bias[n];
    }
  }
}

// ---------------- combine ----------------

__global__ void k_combine(const float* __restrict__ ya, const float* __restrict__ yb,
                          const int* __restrict__ slot_of, const float* __restrict__ topk_gate,
                          float* __restrict__ out){
  int i = blockIdx.x * 256 + threadIdx.x;
  int t = i >> 8;
  int c4 = (i & 255) * 4;
  int s0 = slot_of[2 * t], s1 = slot_of[2 * t + 1];
  float g0 = topk_gate[2 * t], g1 = topk_gate[2 * t + 1];
  float4 a0 = *(const float4*)(ya + (size_t)s0 * DD + c4);
  float4 b0 = *(const float4*)(yb + (size_t)s0 * DD + c4);
  float4 a1 = *(const float4*)(ya + (size_t)s1 * DD + c4);
  float4 b1 = *(const float4*)(yb + (size_t)s1 * DD + c4);
  float4 o;
  o.x = g0 * (a0.x + b0.x) + g1 * (a1.x + b1.x);
  o.y = g0 * (a0.y + b0.y) + g1 * (a1.y + b1.y);
  o.z = g0 * (a0.z + b0.z) + g1 * (a1.z + b1.z);
  o.w = g0 * (a0.w + b0.w) + g1 * (a1.w + b1.w);
  *(float4*)(out + (size_t)t * DD + c4) = o;
}

// ---------------- launch ----------------

extern "C" void kernel_launch(void* const* d_in, const int* in_sizes, int n_in,
                              void* d_out, int out_size, void* d_ws, size_t ws_size,
                              hipStream_t stream){
  (void)in_sizes; (void)n_in; (void)out_size; (void)ws_size;
  const float* x  = (const float*)d_in[0];
  const float* Wg = (const float*)d_in[1];
  const float* W1 = (const float*)d_in[2];
  const float* b1 = (const float*)d_in[3];
  const float* W2 = (const float*)d_in[4];
  const float* b2 = (const float*)d_in[5];
  float* out = (float*)d_out;
  char* ws = (char*)d_ws;

  int*   counts    = (int*)(ws + 0);
  int*   poff      = (int*)(ws + 256);
  int*   topk_idx  = (int*)(ws + 1024);
  float* topk_gate = (float*)(ws + 33792);
  int*   row_token = (int*)(ws + 66560);
  float* row_gate  = (float*)(ws + 103424);
  int*   slot_of   = (int*)(ws + 140288);
  short* xb        = (short*)(ws + 173056);        // 8 MB
  short* h         = (short*)(ws + 142779392);     // 72 MB
  float* ya        = (float*)(ws + 173056);        // aliases xb (dead at gemm2)
  float* yb        = (float*)(ws + 37921792);

  hipMemsetAsync(counts, 0, 32, stream);

  k_prep<<<dim3(NTOK / 4), 256, 0, stream>>>(x, Wg, xb, topk_idx, topk_gate, counts);
  k_route_all<<<dim3(1), 256, 0, stream>>>(counts, topk_idx, topk_gate, poff,
                                           row_token, row_gate, slot_of);
  k_gemm1<<<dim3(ROWTILES * (FF / BN)), 256, 0, stream>>>(xb, W1, b1, h, row_token, poff);
  k_gemm2<<<dim3(ROWTILES * (DD / BN) * KP2), 256, 0, stream>>>(h, W2, b2, ya, yb, poff);
  k_combine<<<dim3(NTOK * DD / 4 / 256), 256, 0, stream>>>(ya, yb, slot_of, topk_gate, out);
}

// Round 23
// 451.127 us; speedup vs baseline: 1.0078x; 1.0078x over previous
//
#include <hip/hip_runtime.h>
#include <hip/hip_bf16.h>
#include <math.h>

// Problem constants
#define NB 2
#define NT 2048
#define NTOK 4096      // NB*NT
#define DD 1024
#define FF 4096
#define NE 8
#define KSEL 2
#define BM 128
#define BN 128
#define BK 32          // K-step (double-buffered)
#define ROWCAP 9216    // 72 tiles * 128
#define ROWTILES 72
#define KP2 2          // split-K factor for GEMM2
#define BSTR 34        // B LDS row stride in shorts (17 dwords)

typedef __attribute__((ext_vector_type(8))) short short8_t;
typedef __attribute__((ext_vector_type(4))) float f32x4;

__device__ __forceinline__ unsigned short f2bf(float f){
  unsigned u = __float_as_uint(f);
  unsigned r = (u + 0x7fffu + ((u >> 16) & 1u)) >> 16;
  return (unsigned short)r;
}

// pack two f32 -> (bf16(a) | bf16(b)<<16), round-half-up (margin-safe vs RNE)
__device__ __forceinline__ unsigned pk2(float a, float b){
  return ((__float_as_uint(a) + 0x8000u) >> 16) | ((__float_as_uint(b) + 0x8000u) & 0xffff0000u);
}

// bijective XCD-chunked swizzle (m204)
__device__ __forceinline__ int xcd_swz(int lin, int nwg){
  int q = nwg >> 3, r = nwg & 7;
  int xcd = lin & 7, idx = lin >> 3;
  return (xcd < r ? xcd * (q + 1) : r * (q + 1) + (xcd - r) * q) + idx;
}

#define GLOAD_LDS(g, l) \
  __builtin_amdgcn_global_load_lds((const __attribute__((address_space(1))) void*)(g), \
                                   (__attribute__((address_space(3))) void*)(l), 16, 0, 0)
#define VMCNT0 asm volatile("s_waitcnt vmcnt(0)" ::: "memory")
#define LGKM0  asm volatile("s_waitcnt lgkmcnt(0)" ::: "memory")
#define RAWBAR __builtin_amdgcn_s_barrier()

// ---------------- prep: convert x -> bf16, gating logits + top2 ----------------

__global__ void k_prep(const float* __restrict__ x, const float* __restrict__ wg,
                       short* __restrict__ xb, int* __restrict__ topk_idx,
                       float* __restrict__ topk_gate, int* __restrict__ counts){
  int wid = threadIdx.x >> 6, lane = threadIdx.x & 63;
  int t = blockIdx.x * 4 + wid;
  const float* xr = x + (size_t)t * DD;
  short* xbr = xb + (size_t)t * DD;
  double acc[NE];
#pragma unroll
  for (int e = 0; e < NE; ++e) acc[e] = 0.0;
#pragma unroll
  for (int p = 0; p < 4; ++p){
    int d = p * 256 + lane * 4;
    float4 v = *(const float4*)(xr + d);
    short4 o;
    o.x = (short)f2bf(v.x); o.y = (short)f2bf(v.y);
    o.z = (short)f2bf(v.z); o.w = (short)f2bf(v.w);
    *(short4*)(xbr + d) = o;
    const float* w0 = wg + (size_t)d * NE;
    float vv[4] = {v.x, v.y, v.z, v.w};
#pragma unroll
    for (int j = 0; j < 4; ++j){
      double xv = (double)vv[j];
#pragma unroll
      for (int e = 0; e < NE; ++e) acc[e] += xv * (double)w0[j * NE + e];
    }
  }
#pragma unroll
  for (int e = 0; e < NE; ++e){
#pragma unroll
    for (int s = 32; s; s >>= 1) acc[e] += __shfl_xor(acc[e], s, 64);
  }
  if (lane == 0){
    int i0 = 0; double v0 = acc[0];
#pragma unroll
    for (int e = 1; e < NE; ++e) if (acc[e] > v0){ v0 = acc[e]; i0 = e; }
    int i1 = -1; double v1 = -1e300;
#pragma unroll
    for (int e = 0; e < NE; ++e) if (e != i0 && acc[e] > v1){ v1 = acc[e]; i1 = e; }
    double g0 = 1.0 / (1.0 + exp(v1 - v0));
    topk_idx[2 * t] = i0; topk_idx[2 * t + 1] = i1;
    topk_gate[2 * t] = (float)g0; topk_gate[2 * t + 1] = (float)(1.0 - g0);
    atomicAdd(&counts[i0], 1);
    atomicAdd(&counts[i1], 1);
  }
}

// ---------------- routing (single block) ----------------

__global__ void k_route_all(const int* __restrict__ counts, const int* __restrict__ topk_idx,
                            const float* __restrict__ topk_gate, int* __restrict__ poff_g,
                            int* __restrict__ row_token, float* __restrict__ row_gate,
                            int* __restrict__ slot_of){
  __shared__ int poff[NE + 1], cur[NE], rends[NE];
  if (threadIdx.x == 0){
    int off = 0;
    for (int e = 0; e < NE; ++e){
      poff[e] = off; cur[e] = off; rends[e] = off + counts[e];
      off += (counts[e] + BM - 1) & ~(BM - 1);
    }
    poff[NE] = off;
    for (int e = 0; e <= NE; ++e) poff_g[e] = poff[e];
  }
  __syncthreads();
  for (int t = threadIdx.x; t < NTOK; t += 256){
#pragma unroll
    for (int k = 0; k < KSEL; ++k){
      int e = topk_idx[2 * t + k];
      float g = topk_gate[2 * t + k];
      int slot = atomicAdd(&cur[e], 1);
      row_token[slot] = t;
      row_gate[slot] = g;
      slot_of[2 * t + k] = slot;
    }
  }
  __syncthreads();
#pragma unroll
  for (int e = 0; e < NE; ++e)
    for (int s = rends[e] + (int)threadIdx.x; s < poff[e + 1]; s += 256){
      row_token[s] = 0; row_gate[s] = 0.f;
    }
}

// ---------------- GEMM1: h = gelu(X_gather @ W1[e] + b1[e]) ----------------
// B staged from f32 W1 directly; conflict-free PACKW: column = kp ^ ((nc>>2&1)<<2)
// -> write banks 8q+4b+kp cover all 32, 2 lanes each. Read applies same XOR.

__launch_bounds__(256, 4)
__global__ void k_gemm1(const short* __restrict__ xb, const float* __restrict__ W1,
                        const float* __restrict__ b1, short* __restrict__ h,
                        const int* __restrict__ row_token, const int* __restrict__ poff){
  __shared__ short As[2][BM * BK];     // 2 x 8 KB
  __shared__ short Bs[2][BN * BSTR];   // 2 x 8704 B
  int wg = xcd_swz(blockIdx.x, ROWTILES * (FF / BN));
  int g = wg >> 6, t6 = wg & 63;
  int bx = (g >> 2) * 8 + (t6 & 7);
  int by = (g & 3) * 8 + (t6 >> 3);
  int row0 = bx * BM;
  if (row0 >= poff[NE]) return;
  int e = 0;
  while (row0 >= poff[e + 1]) ++e;
  int n0 = by * BN;
  int tid = threadIdx.x;

  const short* asrc[2];
#pragma unroll
  for (int p = 0; p < 2; ++p){
    int L = p * 256 + tid;
    int r = L >> 2, c = L & 3;
    int cd = c ^ ((r >> 1) & 3);
    int tok = row_token[row0 + r];
    asrc[p] = xb + (size_t)tok * DD + cd * 8;
  }
  int nc = tid & 15, kp = tid >> 4;           // nc 0..15, kp 0..15 (k = 2kp)
  int wcol = kp ^ (((nc >> 2) & 1) << 2);     // bank-spreading column
  const float* bsrcf = W1 + (size_t)e * DD * FF + (size_t)(2 * kp) * FF + n0 + nc * 8;

  f32x4 acc[4][4];
#pragma unroll
  for (int i = 0; i < 4; ++i)
#pragma unroll
    for (int j = 0; j < 4; ++j) acc[i][j] = (f32x4){0.f, 0.f, 0.f, 0.f};

  int wid = tid >> 6, lane = tid & 63;
  int wr = wid >> 1, wc = wid & 1;
  int lrow = lane & 15, lk = lane >> 4;

  auto STAGE_A = [&](int nb, int k0){
#pragma unroll
    for (int p = 0; p < 2; ++p)
      GLOAD_LDS(asrc[p] + k0, &As[nb][0] + tid * 8 + p * 2048);
  };
  float4 rb0, rb1, rb2, rb3;
  auto LOADB = [&](int k0){
    const float* s = bsrcf + (size_t)k0 * FF;
    rb0 = *(const float4*)(s);
    rb1 = *(const float4*)(s + 4);
    rb2 = *(const float4*)(s + FF);
    rb3 = *(const float4*)(s + FF + 4);
  };
  auto PACKW = [&](int nb){
    int* Bw = (int*)(&Bs[nb][0]);
    int n8 = nc * 8;
    Bw[(n8 + 0) * 17 + wcol] = pk2(rb0.x, rb2.x);
    Bw[(n8 + 1) * 17 + wcol] = pk2(rb0.y, rb2.y);
    Bw[(n8 + 2) * 17 + wcol] = pk2(rb0.z, rb2.z);
    Bw[(n8 + 3) * 17 + wcol] = pk2(rb0.w, rb2.w);
    Bw[(n8 + 4) * 17 + wcol] = pk2(rb1.x, rb3.x);
    Bw[(n8 + 5) * 17 + wcol] = pk2(rb1.y, rb3.y);
    Bw[(n8 + 6) * 17 + wcol] = pk2(rb1.z, rb3.z);
    Bw[(n8 + 7) * 17 + wcol] = pk2(rb1.w, rb3.w);
  };

  // prologue: tile 0 -> buf 0
  LOADB(0);
  STAGE_A(0, 0);
  VMCNT0;
  PACKW(0);
  LGKM0; RAWBAR;

  const int NKT = DD / BK;   // 32
#pragma unroll 1
  for (int kt = 0; kt < NKT; ++kt){
    int b = kt & 1;
    bool more = (kt + 1 < NKT);
    if (more){ LOADB((kt + 1) * BK); STAGE_A(b ^ 1, (kt + 1) * BK); }
    short8_t a[4], bb[4];
#pragma unroll
    for (int m = 0; m < 4; ++m){
      int r = wr * 64 + m * 16 + lrow;
      a[m] = *(const short8_t*)(&As[b][0] + r * BK + ((lk ^ ((r >> 1) & 3)) * 8));
    }
    const int* Bi = (const int*)(&Bs[b][0]);
#pragma unroll
    for (int n = 0; n < 4; ++n){
      int rn = wc * 64 + n * 16 + lrow;
      int bi = rn * 17 + ((lk * 4) ^ (((rn >> 5) & 1) << 2));
      int4 w4;
      w4.x = Bi[bi]; w4.y = Bi[bi + 1]; w4.z = Bi[bi + 2]; w4.w = Bi[bi + 3];
      bb[n] = *(short8_t*)&w4;
    }
#pragma unroll
    for (int m = 0; m < 4; ++m)
#pragma unroll
      for (int n = 0; n < 4; ++n)
        acc[m][n] = __builtin_amdgcn_mfma_f32_16x16x32_bf16(a[m], bb[n], acc[m][n], 0, 0, 0);
    if (more){ VMCNT0; PACKW(b ^ 1); }
    LGKM0; RAWBAR;
  }

  const float* b1e = b1 + (size_t)e * FF;
  float bias[4];
#pragma unroll
  for (int n = 0; n < 4; ++n) bias[n] = b1e[n0 + wc * 64 + n * 16 + lrow];
#pragma unroll
  for (int m = 0; m < 4; ++m){
#pragma unroll
    for (int j = 0; j < 4; ++j){
      int row = row0 + wr * 64 + m * 16 + lk * 4 + j;
      short* hr = h + (size_t)row * FF + n0 + wc * 64 + lrow;
#pragma unroll
      for (int n = 0; n < 4; ++n){
        float v = acc[m][n][j] + bias[n];
        float u = 0.7978845608028654f * (v + 0.044715f * v * v * v);
        float gl = v / (1.0f + __expf(-2.0f * u));   // = 0.5v(1+tanh(u))
        hr[n * 16] = (short)f2bf(gl);
      }
    }
  }
}

// ---------------- GEMM2 (split-K, non-atomic): same direct-W2 B staging ----------------

__launch_bounds__(256, 4)
__global__ void k_gemm2(const short* __restrict__ h, const float* __restrict__ W2,
                        const float* __restrict__ b2, float* __restrict__ ya,
                        float* __restrict__ yb, const int* __restrict__ poff){
  __shared__ short As[2][BM * BK];
  __shared__ short Bs[2][BN * BSTR];
  int wg = xcd_swz(blockIdx.x, ROWTILES * (DD / BN) * KP2);
  int kz = wg / (ROWTILES * (DD / BN));
  int c5 = wg % (ROWTILES * (DD / BN));
  int g = c5 >> 5, t5 = c5 & 31;
  int bx = g * 4 + (t5 & 3);
  int by = t5 >> 2;
  int row0 = bx * BM;
  if (row0 >= poff[NE]) return;
  int e = 0;
  while (row0 >= poff[e + 1]) ++e;
  int n0 = by * BN;
  int tid = threadIdx.x;
  int kbeg = kz * (FF / KP2);

  const short* asrc[2];
#pragma unroll
  for (int p = 0; p < 2; ++p){
    int L = p * 256 + tid;
    int r = L >> 2, c = L & 3;
    int cd = c ^ ((r >> 1) & 3);
    asrc[p] = h + (size_t)(row0 + r) * FF + kbeg + cd * 8;
  }
  int nc = tid & 15, kp = tid >> 4;
  int wcol = kp ^ (((nc >> 2) & 1) << 2);
  const float* bsrcf = W2 + (size_t)e * FF * DD + (size_t)(kbeg + 2 * kp) * DD + n0 + nc * 8;

  f32x4 acc[4][4];
#pragma unroll
  for (int i = 0; i < 4; ++i)
#pragma unroll
    for (int j = 0; j < 4; ++j) acc[i][j] = (f32x4){0.f, 0.f, 0.f, 0.f};

  int wid = tid >> 6, lane = tid & 63;
  int wr = wid >> 1, wc = wid & 1;
  int lrow = lane & 15, lk = lane >> 4;

  auto STAGE_A = [&](int nb, int k0){
#pragma unroll
    for (int p = 0; p < 2; ++p)
      GLOAD_LDS(asrc[p] + k0, &As[nb][0] + tid * 8 + p * 2048);
  };
  float4 rb0, rb1, rb2, rb3;
  auto LOADB = [&](int k0){
    const float* s = bsrcf + (size_t)k0 * DD;
    rb0 = *(const float4*)(s);
    rb1 = *(const float4*)(s + 4);
    rb2 = *(const float4*)(s + DD);
    rb3 = *(const float4*)(s + DD + 4);
  };
  auto PACKW = [&](int nb){
    int* Bw = (int*)(&Bs[nb][0]);
    int n8 = nc * 8;
    Bw[(n8 + 0) * 17 + wcol] = pk2(rb0.x, rb2.x);
    Bw[(n8 + 1) * 17 + wcol] = pk2(rb0.y, rb2.y);
    Bw[(n8 + 2) * 17 + wcol] = pk2(rb0.z, rb2.z);
    Bw[(n8 + 3) * 17 + wcol] = pk2(rb0.w, rb2.w);
    Bw[(n8 + 4) * 17 + wcol] = pk2(rb1.x, rb3.x);
    Bw[(n8 + 5) * 17 + wcol] = pk2(rb1.y, rb3.y);
    Bw[(n8 + 6) * 17 + wcol] = pk2(rb1.z, rb3.z);
    Bw[(n8 + 7) * 17 + wcol] = pk2(rb1.w, rb3.w);
  };

  LOADB(0);
  STAGE_A(0, 0);
  VMCNT0;
  PACKW(0);
  LGKM0; RAWBAR;

  const int NKT = (FF / KP2) / BK;   // 64
#pragma unroll 1
  for (int kt = 0; kt < NKT; ++kt){
    int b = kt & 1;
    bool more = (kt + 1 < NKT);
    if (more){ LOADB((kt + 1) * BK); STAGE_A(b ^ 1, (kt + 1) * BK); }
    short8_t a[4], bb[4];
#pragma unroll
    for (int m = 0; m < 4; ++m){
      int r = wr * 64 + m * 16 + lrow;
      a[m] = *(const short8_t*)(&As[b][0] + r * BK + ((lk ^ ((r >> 1) & 3)) * 8));
    }
    const int* Bi = (const int*)(&Bs[b][0]);
#pragma unroll
    for (int n = 0; n < 4; ++n){
      int rn = wc * 64 + n * 16 + lrow;
      int bi = rn * 17 + ((lk * 4) ^ (((rn >> 5) & 1) << 2));
      int4 w4;
      w4.x = Bi[bi]; w4.y = Bi[bi + 1]; w4.z = Bi[bi + 2]; w4.w = Bi[bi + 3];
      bb[n] = *(short8_t*)&w4;
    }
#pragma unroll
    for (int m = 0; m < 4; ++m)
#pragma unroll
      for (int n = 0; n < 4; ++n)
        acc[m][n] = __builtin_amdgcn_mfma_f32_16x16x32_bf16(a[m], bb[n], acc[m][n], 0, 0, 0);
    if (more){ VMCNT0; PACKW(b ^ 1); }
    LGKM0; RAWBAR;
  }

  float* y = (kz == 0) ? ya : yb;
  const float* b2e = b2 + (size_t)e * DD;
  float bias[4];
#pragma unroll
  for (int n = 0; n < 4; ++n) bias[n] = (kz == 0) ? b2e[n0 + wc * 64 + n * 16 + lrow] : 0.0f;
#pragma unroll
  for (int m = 0; m < 4; ++m){
#pragma unroll
    for (int j = 0; j < 4; ++j){
      int row = row0 + wr * 64 + m * 16 + lk * 4 + j;
      float* yr = y + (size_t)row * DD + n0 + wc * 64 + lrow;
#pragma unroll
      for (int n = 0; n < 4; ++n)
        yr[n * 16] = acc[m][n][j] + bias[n];
    }
  }
}

// ---------------- combine ----------------

__global__ void k_combine(const float* __restrict__ ya, const float* __restrict__ yb,
                          const int* __restrict__ slot_of, const float* __restrict__ topk_gate,
                          float* __restrict__ out){
  int i = blockIdx.x * 256 + threadIdx.x;
  int t = i >> 8;
  int c4 = (i & 255) * 4;
  int s0 = slot_of[2 * t], s1 = slot_of[2 * t + 1];
  float g0 = topk_gate[2 * t], g1 = topk_gate[2 * t + 1];
  float4 a0 = *(const float4*)(ya + (size_t)s0 * DD + c4);
  float4 b0 = *(const float4*)(yb + (size_t)s0 * DD + c4);
  float4 a1 = *(const float4*)(ya + (size_t)s1 * DD + c4);
  float4 b1 = *(const float4*)(yb + (size_t)s1 * DD + c4);
  float4 o;
  o.x = g0 * (a0.x + b0.x) + g1 * (a1.x + b1.x);
  o.y = g0 * (a0.y + b0.y) + g1 * (a1.y + b1.y);
  o.z = g0 * (a0.z + b0.z) + g1 * (a1.z + b1.z);
  o.w = g0 * (a0.w + b0.w) + g1 * (a1.w + b1.w);
  *(float4*)(out + (size_t)t * DD + c4) = o;
}

// ---------------- launch ----------------

extern "C" void kernel_launch(void* const* d_in, const int* in_sizes, int n_in,
                              void* d_out, int out_size, void* d_ws, size_t ws_size,
                              hipStream_t stream){
  (void)in_sizes; (void)n_in; (void)out_size; (void)ws_size;
  const float* x  = (const float*)d_in[0];
  const float* Wg = (const float*)d_in[1];
  const float* W1 = (const float*)d_in[2];
  const float* b1 = (const float*)d_in[3];
  const float* W2 = (const float*)d_in[4];
  const float* b2 = (const float*)d_in[5];
  float* out = (float*)d_out;
  char* ws = (char*)d_ws;

  int*   counts    = (int*)(ws + 0);
  int*   poff      = (int*)(ws + 256);
  int*   topk_idx  = (int*)(ws + 1024);
  float* topk_gate = (float*)(ws + 33792);
  int*   row_token = (int*)(ws + 66560);
  float* row_gate  = (float*)(ws + 103424);
  int*   slot_of   = (int*)(ws + 140288);
  short* xb        = (short*)(ws + 173056);        // 8 MB
  short* h         = (short*)(ws + 142779392);     // 72 MB
  float* ya        = (float*)(ws + 173056);        // aliases xb (dead at gemm2)
  float* yb        = (float*)(ws + 37921792);

  hipMemsetAsync(counts, 0, 32, stream);

  k_prep<<<dim3(NTOK / 4), 256, 0, stream>>>(x, Wg, xb, topk_idx, topk_gate, counts);
  k_route_all<<<dim3(1), 256, 0, stream>>>(counts, topk_idx, topk_gate, poff,
                                           row_token, row_gate, slot_of);
  k_gemm1<<<dim3(ROWTILES * (FF / BN)), 256, 0, stream>>>(xb, W1, b1, h, row_token, poff);
  k_gemm2<<<dim3(ROWTILES * (DD / BN) * KP2), 256, 0, stream>>>(h, W2, b2, ya, yb, poff);
  k_combine<<<dim3(NTOK * DD / 4 / 256), 256, 0, stream>>>(ya, yb, slot_of, topk_gate, out);
}

// Round 24
// 413.989 us; speedup vs baseline: 1.0982x; 1.0897x over previous
//
#include <hip/hip_runtime.h>
#include <hip/hip_bf16.h>
#include <math.h>

// Problem constants
#define NB 2
#define NT 2048
#define NTOK 4096      // NB*NT
#define DD 1024
#define FF 4096
#define NE 8
#define KSEL 2
#define BM 128
#define BN 128
#define BK 32          // K-step (double-buffered; 2 tiles = 32 KB LDS total)
#define ROWCAP 9216    // 72 tiles * 128
#define ROWTILES 72
#define KP2 2          // split-K factor for GEMM2

typedef __attribute__((ext_vector_type(8))) short short8_t;
typedef __attribute__((ext_vector_type(4))) float f32x4;

__device__ __forceinline__ unsigned short f2bf(float f){
  unsigned u = __float_as_uint(f);
  unsigned r = (u + 0x7fffu + ((u >> 16) & 1u)) >> 16;
  return (unsigned short)r;
}

// bijective XCD-chunked swizzle (m204)
__device__ __forceinline__ int xcd_swz(int lin, int nwg){
  int q = nwg >> 3, r = nwg & 7;
  int xcd = lin & 7, idx = lin >> 3;
  return (xcd < r ? xcd * (q + 1) : r * (q + 1) + (xcd - r) * q) + idx;
}

#define GLOAD_LDS(g, l) \
  __builtin_amdgcn_global_load_lds((const __attribute__((address_space(1))) void*)(g), \
                                   (__attribute__((address_space(3))) void*)(l), 16, 0, 0)
#define VMCNT0 asm volatile("s_waitcnt vmcnt(0)" ::: "memory")
#define RAWBAR __builtin_amdgcn_s_barrier()

// ---------------- fused prep (blocks 0..1023) + weight transpose (1024..9215) ----------------
// T stride 134 shorts (67 words, 67%32=3): store-phase banks stride 12 -> <=2-way (free).

__global__ void k_prep_transpose(const float* __restrict__ x, const float* __restrict__ wg,
                                 short* __restrict__ xb, int* __restrict__ topk_idx,
                                 float* __restrict__ topk_gate, int* __restrict__ counts,
                                 const float* __restrict__ W1, const float* __restrict__ W2,
                                 short* __restrict__ w1t, short* __restrict__ w2t){
  __shared__ short T[64][134];
  if (blockIdx.x < 1024){
    // ---- prep: convert x -> bf16, gating logits + top2 ----
    int wid = threadIdx.x >> 6, lane = threadIdx.x & 63;
    int t = blockIdx.x * 4 + wid;
    const float* xr = x + (size_t)t * DD;
    short* xbr = xb + (size_t)t * DD;
    double acc[NE];
#pragma unroll
    for (int e = 0; e < NE; ++e) acc[e] = 0.0;
#pragma unroll
    for (int p = 0; p < 4; ++p){
      int d = p * 256 + lane * 4;
      float4 v = *(const float4*)(xr + d);
      short4 o;
      o.x = (short)f2bf(v.x); o.y = (short)f2bf(v.y);
      o.z = (short)f2bf(v.z); o.w = (short)f2bf(v.w);
      *(short4*)(xbr + d) = o;
      const float* w0 = wg + (size_t)d * NE;
      float vv[4] = {v.x, v.y, v.z, v.w};
#pragma unroll
      for (int j = 0; j < 4; ++j){
        double xv = (double)vv[j];
#pragma unroll
        for (int e = 0; e < NE; ++e) acc[e] += xv * (double)w0[j * NE + e];
      }
    }
#pragma unroll
    for (int e = 0; e < NE; ++e){
#pragma unroll
      for (int s = 32; s; s >>= 1) acc[e] += __shfl_xor(acc[e], s, 64);
    }
    if (lane == 0){
      int i0 = 0; double v0 = acc[0];
#pragma unroll
      for (int e = 1; e < NE; ++e) if (acc[e] > v0){ v0 = acc[e]; i0 = e; }
      int i1 = -1; double v1 = -1e300;
#pragma unroll
      for (int e = 0; e < NE; ++e) if (e != i0 && acc[e] > v1){ v1 = acc[e]; i1 = e; }
      double g0 = 1.0 / (1.0 + exp(v1 - v0));
      topk_idx[2 * t] = i0; topk_idx[2 * t + 1] = i1;
      topk_gate[2 * t] = (float)g0; topk_gate[2 * t + 1] = (float)(1.0 - g0);
      atomicAdd(&counts[i0], 1);
      atomicAdd(&counts[i1], 1);
    }
    return;
  }
  // ---- transpose+convert: W1 [E][D][F]->w1t [E][F][D]; W2 [E][F][D]->w2t [E][D][F] ----
  int id = blockIdx.x - 1024;
  bool isW2 = id >= 4096;
  int rem = id & 4095;
  int e = rem >> 9;
  int tr = rem & 511;
  int R, C, c0, r0;
  const float* in; short* out;
  if (!isW2){ R = DD; C = FF; c0 = (tr & 63) * 64; r0 = (tr >> 6) * 128;
              in = W1 + (size_t)e * R * C; out = w1t + (size_t)e * R * C; }
  else      { R = FF; C = DD; c0 = (tr & 15) * 64; r0 = (tr >> 4) * 128;
              in = W2 + (size_t)e * R * C; out = w2t + (size_t)e * R * C; }
  int t = threadIdx.x;
  int rr = t >> 4, c4 = (t & 15) * 4;
#pragma unroll
  for (int p = 0; p < 8; ++p){
    int row = p * 16 + rr;
    float4 v = *(const float4*)(in + (size_t)(r0 + row) * C + c0 + c4);
    T[c4 + 0][row] = (short)f2bf(v.x);
    T[c4 + 1][row] = (short)f2bf(v.y);
    T[c4 + 2][row] = (short)f2bf(v.z);
    T[c4 + 3][row] = (short)f2bf(v.w);
  }
  __syncthreads();
  int c8 = (t & 15) * 8;
#pragma unroll
  for (int q = 0; q < 4; ++q){
    int orow = q * 16 + rr;
    short4 lo = *(const short4*)&T[orow][c8];
    short4 hi = *(const short4*)&T[orow][c8 + 4];
    short8_t w;
    w[0] = lo.x; w[1] = lo.y; w[2] = lo.z; w[3] = lo.w;
    w[4] = hi.x; w[5] = hi.y; w[6] = hi.z; w[7] = hi.w;
    *(short8_t*)(out + (size_t)(c0 + orow) * R + r0 + c8) = w;
  }
}

// ---------------- routing (single block) ----------------

__global__ void k_route_all(const int* __restrict__ counts, const int* __restrict__ topk_idx,
                            const float* __restrict__ topk_gate, int* __restrict__ poff_g,
                            int* __restrict__ row_token, float* __restrict__ row_gate,
                            int* __restrict__ slot_of){
  __shared__ int poff[NE + 1], cur[NE], rends[NE];
  if (threadIdx.x == 0){
    int off = 0;
    for (int e = 0; e < NE; ++e){
      poff[e] = off; cur[e] = off; rends[e] = off + counts[e];
      off += (counts[e] + BM - 1) & ~(BM - 1);
    }
    poff[NE] = off;
    for (int e = 0; e <= NE; ++e) poff_g[e] = poff[e];
  }
  __syncthreads();
  for (int t = threadIdx.x; t < NTOK; t += 256){
#pragma unroll
    for (int k = 0; k < KSEL; ++k){
      int e = topk_idx[2 * t + k];
      float g = topk_gate[2 * t + k];
      int slot = atomicAdd(&cur[e], 1);
      row_token[slot] = t;
      row_gate[slot] = g;
      slot_of[2 * t + k] = slot;
    }
  }
  __syncthreads();
#pragma unroll
  for (int e = 0; e < NE; ++e)
    for (int s = rends[e] + (int)threadIdx.x; s < poff[e + 1]; s += 256){
      row_token[s] = 0; row_gate[s] = 0.f;
    }
}

// ---------------- GEMM1: h = gelu(X_gather @ W1[e] + b1[e]) ----------------
// BK=32 double-buffer, 2-phase; conflict-free swizzle s(r)=(r>>1)&3 (r13-proven).

__launch_bounds__(256, 4)
__global__ void k_gemm1(const short* __restrict__ xb, const short* __restrict__ w1t,
                        const float* __restrict__ b1, short* __restrict__ h,
                        const int* __restrict__ row_token, const int* __restrict__ poff){
  __shared__ short As[2][BM * BK];   // 2 x 8 KB
  __shared__ short Bs[2][BN * BK];   // 2 x 8 KB
  int wg = xcd_swz(blockIdx.x, ROWTILES * (FF / BN));
  int g = wg >> 6, t6 = wg & 63;
  int bx = (g >> 2) * 8 + (t6 & 7);
  int by = (g & 3) * 8 + (t6 >> 3);
  int row0 = bx * BM;
  if (row0 >= poff[NE]) return;
  int e = 0;
  while (row0 >= poff[e + 1]) ++e;
  int n0 = by * BN;
  int tid = threadIdx.x;

  const short* asrc[2]; const short* bsrc[2];
#pragma unroll
  for (int p = 0; p < 2; ++p){
    int L = p * 256 + tid;
    int r = L >> 2, c = L & 3;
    int cd = c ^ ((r >> 1) & 3);
    int tok = row_token[row0 + r];
    asrc[p] = xb + (size_t)tok * DD + cd * 8;
    bsrc[p] = w1t + (size_t)e * FF * DD + (size_t)(n0 + r) * DD + cd * 8;
  }

  f32x4 acc[4][4];
#pragma unroll
  for (int i = 0; i < 4; ++i)
#pragma unroll
    for (int j = 0; j < 4; ++j) acc[i][j] = (f32x4){0.f, 0.f, 0.f, 0.f};

  int wid = tid >> 6, lane = tid & 63;
  int wr = wid >> 1, wc = wid & 1;
  int lrow = lane & 15, lk = lane >> 4;

  auto STAGE = [&](int nb, int k0){
#pragma unroll
    for (int p = 0; p < 2; ++p){
      GLOAD_LDS(asrc[p] + k0, &As[nb][0] + tid * 8 + p * 2048);
      GLOAD_LDS(bsrc[p] + k0, &Bs[nb][0] + tid * 8 + p * 2048);
    }
  };

  STAGE(0, 0);
  VMCNT0; RAWBAR;

  const int NKT = DD / BK;   // 32
#pragma unroll 1
  for (int kt = 0; kt < NKT; ++kt){
    int b = kt & 1;
    bool more = (kt + 1 < NKT);
    if (more) STAGE(b ^ 1, (kt + 1) * BK);
    short8_t a[4], bb[4];
#pragma unroll
    for (int m = 0; m < 4; ++m){
      int r = wr * 64 + m * 16 + lrow;
      a[m] = *(const short8_t*)(&As[b][0] + r * BK + ((lk ^ ((r >> 1) & 3)) * 8));
    }
#pragma unroll
    for (int n = 0; n < 4; ++n){
      int r = wc * 64 + n * 16 + lrow;
      bb[n] = *(const short8_t*)(&Bs[b][0] + r * BK + ((lk ^ ((r >> 1) & 3)) * 8));
    }
#pragma unroll
    for (int m = 0; m < 4; ++m)
#pragma unroll
      for (int n = 0; n < 4; ++n)
        acc[m][n] = __builtin_amdgcn_mfma_f32_16x16x32_bf16(a[m], bb[n], acc[m][n], 0, 0, 0);
    if (more) VMCNT0;
    RAWBAR;
  }

  const float* b1e = b1 + (size_t)e * FF;
  float bias[4];
#pragma unroll
  for (int n = 0; n < 4; ++n) bias[n] = b1e[n0 + wc * 64 + n * 16 + lrow];
#pragma unroll
  for (int m = 0; m < 4; ++m){
#pragma unroll
    for (int j = 0; j < 4; ++j){
      int row = row0 + wr * 64 + m * 16 + lk * 4 + j;
      short* hr = h + (size_t)row * FF + n0 + wc * 64 + lrow;
#pragma unroll
      for (int n = 0; n < 4; ++n){
        float v = acc[m][n][j] + bias[n];
        float u = 0.7978845608028654f * (v + 0.044715f * v * v * v);
        float gl = v / (1.0f + __expf(-2.0f * u));   // = 0.5v(1+tanh(u))
        hr[n * 16] = (short)f2bf(gl);
      }
    }
  }
}

// ---------------- GEMM2 (split-K, non-atomic): same BK=32 2-phase loop ----------------

__launch_bounds__(256, 4)
__global__ void k_gemm2(const short* __restrict__ h, const short* __restrict__ w2t,
                        const float* __restrict__ b2, float* __restrict__ ya,
                        float* __restrict__ yb, const int* __restrict__ poff){
  __shared__ short As[2][BM * BK];
  __shared__ short Bs[2][BN * BK];
  int wg = xcd_swz(blockIdx.x, ROWTILES * (DD / BN) * KP2);
  int kz = wg / (ROWTILES * (DD / BN));
  int c5 = wg % (ROWTILES * (DD / BN));
  int g = c5 >> 5, t5 = c5 & 31;
  int bx = g * 4 + (t5 & 3);
  int by = t5 >> 2;
  int row0 = bx * BM;
  if (row0 >= poff[NE]) return;
  int e = 0;
  while (row0 >= poff[e + 1]) ++e;
  int n0 = by * BN;
  int tid = threadIdx.x;

  const short* asrc[2]; const short* bsrc[2];
#pragma unroll
  for (int p = 0; p < 2; ++p){
    int L = p * 256 + tid;
    int r = L >> 2, c = L & 3;
    int cd = c ^ ((r >> 1) & 3);
    asrc[p] = h + (size_t)(row0 + r) * FF + cd * 8;
    bsrc[p] = w2t + (size_t)e * DD * FF + (size_t)(n0 + r) * FF + cd * 8;
  }

  f32x4 acc[4][4];
#pragma unroll
  for (int i = 0; i < 4; ++i)
#pragma unroll
    for (int j = 0; j < 4; ++j) acc[i][j] = (f32x4){0.f, 0.f, 0.f, 0.f};

  int wid = tid >> 6, lane = tid & 63;
  int wr = wid >> 1, wc = wid & 1;
  int lrow = lane & 15, lk = lane >> 4;

  auto STAGE = [&](int nb, int k0){
#pragma unroll
    for (int p = 0; p < 2; ++p){
      GLOAD_LDS(asrc[p] + k0, &As[nb][0] + tid * 8 + p * 2048);
      GLOAD_LDS(bsrc[p] + k0, &Bs[nb][0] + tid * 8 + p * 2048);
    }
  };

  int kbeg = kz * (FF / KP2);
  STAGE(0, kbeg);
  VMCNT0; RAWBAR;

  const int NKT = (FF / KP2) / BK;   // 64
#pragma unroll 1
  for (int kt = 0; kt < NKT; ++kt){
    int b = kt & 1;
    bool more = (kt + 1 < NKT);
    if (more) STAGE(b ^ 1, kbeg + (kt + 1) * BK);
    short8_t a[4], bb[4];
#pragma unroll
    for (int m = 0; m < 4; ++m){
      int r = wr * 64 + m * 16 + lrow;
      a[m] = *(const short8_t*)(&As[b][0] + r * BK + ((lk ^ ((r >> 1) & 3)) * 8));
    }
#pragma unroll
    for (int n = 0; n < 4; ++n){
      int r = wc * 64 + n * 16 + lrow;
      bb[n] = *(const short8_t*)(&Bs[b][0] + r * BK + ((lk ^ ((r >> 1) & 3)) * 8));
    }
#pragma unroll
    for (int m = 0; m < 4; ++m)
#pragma unroll
      for (int n = 0; n < 4; ++n)
        acc[m][n] = __builtin_amdgcn_mfma_f32_16x16x32_bf16(a[m], bb[n], acc[m][n], 0, 0, 0);
    if (more) VMCNT0;
    RAWBAR;
  }

  float* y = (kz == 0) ? ya : yb;
  const float* b2e = b2 + (size_t)e * DD;
  float bias[4];
#pragma unroll
  for (int n = 0; n < 4; ++n) bias[n] = (kz == 0) ? b2e[n0 + wc * 64 + n * 16 + lrow] : 0.0f;
#pragma unroll
  for (int m = 0; m < 4; ++m){
#pragma unroll
    for (int j = 0; j < 4; ++j){
      int row = row0 + wr * 64 + m * 16 + lk * 4 + j;
      float* yr = y + (size_t)row * DD + n0 + wc * 64 + lrow;
#pragma unroll
      for (int n = 0; n < 4; ++n)
        yr[n * 16] = acc[m][n][j] + bias[n];
    }
  }
}

// ---------------- combine ----------------

__global__ void k_combine(const float* __restrict__ ya, const float* __restrict__ yb,
                          const int* __restrict__ slot_of, const float* __restrict__ topk_gate,
                          float* __restrict__ out){
  int i = blockIdx.x * 256 + threadIdx.x;
  int t = i >> 8;
  int c4 = (i & 255) * 4;
  int s0 = slot_of[2 * t], s1 = slot_of[2 * t + 1];
  float g0 = topk_gate[2 * t], g1 = topk_gate[2 * t + 1];
  float4 a0 = *(const float4*)(ya + (size_t)s0 * DD + c4);
  float4 b0 = *(const float4*)(yb + (size_t)s0 * DD + c4);
  float4 a1 = *(const float4*)(ya + (size_t)s1 * DD + c4);
  float4 b1 = *(const float4*)(yb + (size_t)s1 * DD + c4);
  float4 o;
  o.x = g0 * (a0.x + b0.x) + g1 * (a1.x + b1.x);
  o.y = g0 * (a0.y + b0.y) + g1 * (a1.y + b1.y);
  o.z = g0 * (a0.z + b0.z) + g1 * (a1.z + b1.z);
  o.w = g0 * (a0.w + b0.w) + g1 * (a1.w + b1.w);
  *(float4*)(out + (size_t)t * DD + c4) = o;
}

// ---------------- launch ----------------

extern "C" void kernel_launch(void* const* d_in, const int* in_sizes, int n_in,
                              void* d_out, int out_size, void* d_ws, size_t ws_size,
                              hipStream_t stream){
  (void)in_sizes; (void)n_in; (void)out_size; (void)ws_size;
  const float* x  = (const float*)d_in[0];
  const float* Wg = (const float*)d_in[1];
  const float* W1 = (const float*)d_in[2];
  const float* b1 = (const float*)d_in[3];
  const float* W2 = (const float*)d_in[4];
  const float* b2 = (const float*)d_in[5];
  float* out = (float*)d_out;
  char* ws = (char*)d_ws;

  int*   counts    = (int*)(ws + 0);
  int*   poff      = (int*)(ws + 256);
  int*   topk_idx  = (int*)(ws + 1024);
  float* topk_gate = (float*)(ws + 33792);
  int*   row_token = (int*)(ws + 66560);
  float* row_gate  = (float*)(ws + 103424);
  int*   slot_of   = (int*)(ws + 140288);
  short* xb        = (short*)(ws + 173056);
  short* w1t       = (short*)(ws + 8561664);
  short* w2t       = (short*)(ws + 75670528);
  short* h         = (short*)(ws + 142779392);
  float* ya        = (float*)(ws + 173056);
  float* yb        = (float*)(ws + 37921792);

  hipMemsetAsync(counts, 0, 32, stream);

  k_prep_transpose<<<dim3(1024 + 8192), 256, 0, stream>>>(x, Wg, xb, topk_idx, topk_gate,
                                                          counts, W1, W2, w1t, w2t);
  k_route_all<<<dim3(1), 256, 0, stream>>>(counts, topk_idx, topk_gate, poff,
                                           row_token, row_gate, slot_of);
  k_gemm1<<<dim3(ROWTILES * (FF / BN)), 256, 0, stream>>>(xb, w1t, b1, h, row_token, poff);
  k_gemm2<<<dim3(ROWTILES * (DD / BN) * KP2), 256, 0, stream>>>(h, w2t, b2, ya, yb, poff);
  k_combine<<<dim3(NTOK * DD / 4 / 256), 256, 0, stream>>>(ya, yb, slot_of, topk_gate, out);
}

// Round 25
// 405.427 us; speedup vs baseline: 1.1214x; 1.0211x over previous
//
#include <hip/hip_runtime.h>
#include <hip/hip_bf16.h>
#include <math.h>

// Problem constants
#define NB 2
#define NT 2048
#define NTOK 4096      // NB*NT
#define DD 1024
#define FF 4096
#define NE 8
#define KSEL 2
#define BM 128
#define BN 128
#define BK 32          // K-step (double-buffered; 2 tiles = 32 KB LDS total)
#define ROWCAP 9216    // 72 tiles * 128
#define ROWTILES 72
#define KP2 2          // split-K factor for GEMM2
#define NG1 (ROWTILES * (FF / BN))   // 2304 gemm1 blocks

typedef __attribute__((ext_vector_type(8))) short short8_t;
typedef __attribute__((ext_vector_type(4))) float f32x4;

__device__ __forceinline__ unsigned short f2bf(float f){
  unsigned u = __float_as_uint(f);
  unsigned r = (u + 0x7fffu + ((u >> 16) & 1u)) >> 16;
  return (unsigned short)r;
}

// bijective XCD-chunked swizzle (m204)
__device__ __forceinline__ int xcd_swz(int lin, int nwg){
  int q = nwg >> 3, r = nwg & 7;
  int xcd = lin & 7, idx = lin >> 3;
  return (xcd < r ? xcd * (q + 1) : r * (q + 1) + (xcd - r) * q) + idx;
}

#define GLOAD_LDS(g, l) \
  __builtin_amdgcn_global_load_lds((const __attribute__((address_space(1))) void*)(g), \
                                   (__attribute__((address_space(3))) void*)(l), 16, 0, 0)
#define VMCNT0 asm volatile("s_waitcnt vmcnt(0)" ::: "memory")
#define RAWBAR __builtin_amdgcn_s_barrier()

// ---- shared transpose tile body (in [R][C] f32 -> out [C][R] bf16, 128x64 tile) ----
__device__ __forceinline__ void transpose_tile(const float* in, short* out, int R, int C,
                                               int r0, int c0, short (*T)[134], int t){
  int rr = t >> 4, c4 = (t & 15) * 4;
#pragma unroll
  for (int p = 0; p < 8; ++p){
    int row = p * 16 + rr;
    float4 v = *(const float4*)(in + (size_t)(r0 + row) * C + c0 + c4);
    T[c4 + 0][row] = (short)f2bf(v.x);
    T[c4 + 1][row] = (short)f2bf(v.y);
    T[c4 + 2][row] = (short)f2bf(v.z);
    T[c4 + 3][row] = (short)f2bf(v.w);
  }
  __syncthreads();
  int c8 = (t & 15) * 8;
#pragma unroll
  for (int q = 0; q < 4; ++q){
    int orow = q * 16 + rr;
    short4 lo = *(const short4*)&T[orow][c8];
    short4 hi = *(const short4*)&T[orow][c8 + 4];
    short8_t w;
    w[0] = lo.x; w[1] = lo.y; w[2] = lo.z; w[3] = lo.w;
    w[4] = hi.x; w[5] = hi.y; w[6] = hi.z; w[7] = hi.w;
    *(short8_t*)(out + (size_t)(c0 + orow) * R + r0 + c8) = w;
  }
}

// ---------------- fused prep (blocks 0..1023) + W1 transpose (1024..5119) ----------------

__global__ void k_prep_w1t(const float* __restrict__ x, const float* __restrict__ wg,
                           short* __restrict__ xb, int* __restrict__ topk_idx,
                           float* __restrict__ topk_gate, int* __restrict__ counts,
                           const float* __restrict__ W1, short* __restrict__ w1t){
  __shared__ short T[64][134];
  if (blockIdx.x < 1024){
    int wid = threadIdx.x >> 6, lane = threadIdx.x & 63;
    int t = blockIdx.x * 4 + wid;
    const float* xr = x + (size_t)t * DD;
    short* xbr = xb + (size_t)t * DD;
    double acc[NE];
#pragma unroll
    for (int e = 0; e < NE; ++e) acc[e] = 0.0;
#pragma unroll
    for (int p = 0; p < 4; ++p){
      int d = p * 256 + lane * 4;
      float4 v = *(const float4*)(xr + d);
      short4 o;
      o.x = (short)f2bf(v.x); o.y = (short)f2bf(v.y);
      o.z = (short)f2bf(v.z); o.w = (short)f2bf(v.w);
      *(short4*)(xbr + d) = o;
      const float* w0 = wg + (size_t)d * NE;
      float vv[4] = {v.x, v.y, v.z, v.w};
#pragma unroll
      for (int j = 0; j < 4; ++j){
        double xv = (double)vv[j];
#pragma unroll
        for (int e = 0; e < NE; ++e) acc[e] += xv * (double)w0[j * NE + e];
      }
    }
#pragma unroll
    for (int e = 0; e < NE; ++e){
#pragma unroll
      for (int s = 32; s; s >>= 1) acc[e] += __shfl_xor(acc[e], s, 64);
    }
    if (lane == 0){
      int i0 = 0; double v0 = acc[0];
#pragma unroll
      for (int e = 1; e < NE; ++e) if (acc[e] > v0){ v0 = acc[e]; i0 = e; }
      int i1 = -1; double v1 = -1e300;
#pragma unroll
      for (int e = 0; e < NE; ++e) if (e != i0 && acc[e] > v1){ v1 = acc[e]; i1 = e; }
      double g0 = 1.0 / (1.0 + exp(v1 - v0));
      topk_idx[2 * t] = i0; topk_idx[2 * t + 1] = i1;
      topk_gate[2 * t] = (float)g0; topk_gate[2 * t + 1] = (float)(1.0 - g0);
      atomicAdd(&counts[i0], 1);
      atomicAdd(&counts[i1], 1);
    }
    return;
  }
  // W1 [E][D][F] -> w1t [E][F][D]  (R=D=1024, C=F=4096)
  int id = blockIdx.x - 1024;          // 0..4095
  int e = id >> 9, tr = id & 511;
  int c0 = (tr & 63) * 64, r0 = (tr >> 6) * 128;
  transpose_tile(W1 + (size_t)e * DD * FF, w1t + (size_t)e * DD * FF, DD, FF, r0, c0, T,
                 threadIdx.x);
}

// ---------------- routing (single block) ----------------

__global__ void k_route_all(const int* __restrict__ counts, const int* __restrict__ topk_idx,
                            const float* __restrict__ topk_gate, int* __restrict__ poff_g,
                            int* __restrict__ row_token, float* __restrict__ row_gate,
                            int* __restrict__ slot_of){
  __shared__ int poff[NE + 1], cur[NE], rends[NE];
  if (threadIdx.x == 0){
    int off = 0;
    for (int e = 0; e < NE; ++e){
      poff[e] = off; cur[e] = off; rends[e] = off + counts[e];
      off += (counts[e] + BM - 1) & ~(BM - 1);
    }
    poff[NE] = off;
    for (int e = 0; e <= NE; ++e) poff_g[e] = poff[e];
  }
  __syncthreads();
  for (int t = threadIdx.x; t < NTOK; t += 256){
#pragma unroll
    for (int k = 0; k < KSEL; ++k){
      int e = topk_idx[2 * t + k];
      float g = topk_gate[2 * t + k];
      int slot = atomicAdd(&cur[e], 1);
      row_token[slot] = t;
      row_gate[slot] = g;
      slot_of[2 * t + k] = slot;
    }
  }
  __syncthreads();
#pragma unroll
  for (int e = 0; e < NE; ++e)
    for (int s = rends[e] + (int)threadIdx.x; s < poff[e + 1]; s += 256){
      row_token[s] = 0; row_gate[s] = 0.f;
    }
}

// ---------------- FUSED: GEMM1 (blocks 0..2303) + W2 transpose (2304..6399) ----------------
// W2 transpose is independent of gemm1 (w2t consumed only by gemm2) -> co-executes,
// hiding ~89us of transpose under gemm1. LDS overlaid: union of 32KB gemm1 buffers
// and 17KB transpose tile.

__launch_bounds__(256, 4)
__global__ void k_gemm1_w2t(const short* __restrict__ xb, const short* __restrict__ w1t,
                            const float* __restrict__ b1, short* __restrict__ h,
                            const int* __restrict__ row_token, const int* __restrict__ poff,
                            const float* __restrict__ W2, short* __restrict__ w2t){
  __shared__ short smem[16384];   // 32 KB union
  if (blockIdx.x >= NG1){
    // W2 [E][F][D] -> w2t [E][D][F]  (R=F=4096, C=D=1024)
    int id = blockIdx.x - NG1;     // 0..4095
    int e = id >> 9, tr = id & 511;
    int c0 = (tr & 15) * 64, r0 = (tr >> 4) * 128;
    transpose_tile(W2 + (size_t)e * FF * DD, w2t + (size_t)e * FF * DD, FF, DD, r0, c0,
                   (short (*)[134])smem, threadIdx.x);
    return;
  }
  short (*As)[BM * BK] = (short (*)[BM * BK])smem;             // As[2], 16 KB
  short (*Bs)[BN * BK] = (short (*)[BN * BK])(smem + 8192);    // Bs[2], 16 KB
  int wg = xcd_swz(blockIdx.x, NG1);
  int g = wg >> 6, t6 = wg & 63;
  int bx = (g >> 2) * 8 + (t6 & 7);
  int by = (g & 3) * 8 + (t6 >> 3);
  int row0 = bx * BM;
  if (row0 >= poff[NE]) return;
  int e = 0;
  while (row0 >= poff[e + 1]) ++e;
  int n0 = by * BN;
  int tid = threadIdx.x;

  const short* asrc[2]; const short* bsrc[2];
#pragma unroll
  for (int p = 0; p < 2; ++p){
    int L = p * 256 + tid;
    int r = L >> 2, c = L & 3;
    int cd = c ^ ((r >> 1) & 3);
    int tok = row_token[row0 + r];
    asrc[p] = xb + (size_t)tok * DD + cd * 8;
    bsrc[p] = w1t + (size_t)e * FF * DD + (size_t)(n0 + r) * DD + cd * 8;
  }

  f32x4 acc[4][4];
#pragma unroll
  for (int i = 0; i < 4; ++i)
#pragma unroll
    for (int j = 0; j < 4; ++j) acc[i][j] = (f32x4){0.f, 0.f, 0.f, 0.f};

  int wid = tid >> 6, lane = tid & 63;
  int wr = wid >> 1, wc = wid & 1;
  int lrow = lane & 15, lk = lane >> 4;

  auto STAGE = [&](int nb, int k0){
#pragma unroll
    for (int p = 0; p < 2; ++p){
      GLOAD_LDS(asrc[p] + k0, &As[nb][0] + tid * 8 + p * 2048);
      GLOAD_LDS(bsrc[p] + k0, &Bs[nb][0] + tid * 8 + p * 2048);
    }
  };

  STAGE(0, 0);
  VMCNT0; RAWBAR;

  const int NKT = DD / BK;   // 32
#pragma unroll 1
  for (int kt = 0; kt < NKT; ++kt){
    int b = kt & 1;
    bool more = (kt + 1 < NKT);
    if (more) STAGE(b ^ 1, (kt + 1) * BK);
    short8_t a[4], bb[4];
#pragma unroll
    for (int m = 0; m < 4; ++m){
      int r = wr * 64 + m * 16 + lrow;
      a[m] = *(const short8_t*)(&As[b][0] + r * BK + ((lk ^ ((r >> 1) & 3)) * 8));
    }
#pragma unroll
    for (int n = 0; n < 4; ++n){
      int r = wc * 64 + n * 16 + lrow;
      bb[n] = *(const short8_t*)(&Bs[b][0] + r * BK + ((lk ^ ((r >> 1) & 3)) * 8));
    }
#pragma unroll
    for (int m = 0; m < 4; ++m)
#pragma unroll
      for (int n = 0; n < 4; ++n)
        acc[m][n] = __builtin_amdgcn_mfma_f32_16x16x32_bf16(a[m], bb[n], acc[m][n], 0, 0, 0);
    if (more) VMCNT0;
    RAWBAR;
  }

  const float* b1e = b1 + (size_t)e * FF;
  float bias[4];
#pragma unroll
  for (int n = 0; n < 4; ++n) bias[n] = b1e[n0 + wc * 64 + n * 16 + lrow];
#pragma unroll
  for (int m = 0; m < 4; ++m){
#pragma unroll
    for (int j = 0; j < 4; ++j){
      int row = row0 + wr * 64 + m * 16 + lk * 4 + j;
      short* hr = h + (size_t)row * FF + n0 + wc * 64 + lrow;
#pragma unroll
      for (int n = 0; n < 4; ++n){
        float v = acc[m][n][j] + bias[n];
        float u = 0.7978845608028654f * (v + 0.044715f * v * v * v);
        float gl = v / (1.0f + __expf(-2.0f * u));   // = 0.5v(1+tanh(u))
        hr[n * 16] = (short)f2bf(gl);
      }
    }
  }
}

// ---------------- GEMM2 (split-K, non-atomic): BK=32 2-phase loop ----------------

__launch_bounds__(256, 4)
__global__ void k_gemm2(const short* __restrict__ h, const short* __restrict__ w2t,
                        const float* __restrict__ b2, float* __restrict__ ya,
                        float* __restrict__ yb, const int* __restrict__ poff){
  __shared__ short As[2][BM * BK];
  __shared__ short Bs[2][BN * BK];
  int wg = xcd_swz(blockIdx.x, ROWTILES * (DD / BN) * KP2);
  int kz = wg / (ROWTILES * (DD / BN));
  int c5 = wg % (ROWTILES * (DD / BN));
  int g = c5 >> 5, t5 = c5 & 31;
  int bx = g * 4 + (t5 & 3);
  int by = t5 >> 2;
  int row0 = bx * BM;
  if (row0 >= poff[NE]) return;
  int e = 0;
  while (row0 >= poff[e + 1]) ++e;
  int n0 = by * BN;
  int tid = threadIdx.x;

  const short* asrc[2]; const short* bsrc[2];
#pragma unroll
  for (int p = 0; p < 2; ++p){
    int L = p * 256 + tid;
    int r = L >> 2, c = L & 3;
    int cd = c ^ ((r >> 1) & 3);
    asrc[p] = h + (size_t)(row0 + r) * FF + cd * 8;
    bsrc[p] = w2t + (size_t)e * DD * FF + (size_t)(n0 + r) * FF + cd * 8;
  }

  f32x4 acc[4][4];
#pragma unroll
  for (int i = 0; i < 4; ++i)
#pragma unroll
    for (int j = 0; j < 4; ++j) acc[i][j] = (f32x4){0.f, 0.f, 0.f, 0.f};

  int wid = tid >> 6, lane = tid & 63;
  int wr = wid >> 1, wc = wid & 1;
  int lrow = lane & 15, lk = lane >> 4;

  auto STAGE = [&](int nb, int k0){
#pragma unroll
    for (int p = 0; p < 2; ++p){
      GLOAD_LDS(asrc[p] + k0, &As[nb][0] + tid * 8 + p * 2048);
      GLOAD_LDS(bsrc[p] + k0, &Bs[nb][0] + tid * 8 + p * 2048);
    }
  };

  int kbeg = kz * (FF / KP2);
  STAGE(0, kbeg);
  VMCNT0; RAWBAR;

  const int NKT = (FF / KP2) / BK;   // 64
#pragma unroll 1
  for (int kt = 0; kt < NKT; ++kt){
    int b = kt & 1;
    bool more = (kt + 1 < NKT);
    if (more) STAGE(b ^ 1, kbeg + (kt + 1) * BK);
    short8_t a[4], bb[4];
#pragma unroll
    for (int m = 0; m < 4; ++m){
      int r = wr * 64 + m * 16 + lrow;
      a[m] = *(const short8_t*)(&As[b][0] + r * BK + ((lk ^ ((r >> 1) & 3)) * 8));
    }
#pragma unroll
    for (int n = 0; n < 4; ++n){
      int r = wc * 64 + n * 16 + lrow;
      bb[n] = *(const short8_t*)(&Bs[b][0] + r * BK + ((lk ^ ((r >> 1) & 3)) * 8));
    }
#pragma unroll
    for (int m = 0; m < 4; ++m)
#pragma unroll
      for (int n = 0; n < 4; ++n)
        acc[m][n] = __builtin_amdgcn_mfma_f32_16x16x32_bf16(a[m], bb[n], acc[m][n], 0, 0, 0);
    if (more) VMCNT0;
    RAWBAR;
  }

  float* y = (kz == 0) ? ya : yb;
  const float* b2e = b2 + (size_t)e * DD;
  float bias[4];
#pragma unroll
  for (int n = 0; n < 4; ++n) bias[n] = (kz == 0) ? b2e[n0 + wc * 64 + n * 16 + lrow] : 0.0f;
#pragma unroll
  for (int m = 0; m < 4; ++m){
#pragma unroll
    for (int j = 0; j < 4; ++j){
      int row = row0 + wr * 64 + m * 16 + lk * 4 + j;
      float* yr = y + (size_t)row * DD + n0 + wc * 64 + lrow;
#pragma unroll
      for (int n = 0; n < 4; ++n)
        yr[n * 16] = acc[m][n][j] + bias[n];
    }
  }
}

// ---------------- combine ----------------

__global__ void k_combine(const float* __restrict__ ya, const float* __restrict__ yb,
                          const int* __restrict__ slot_of, const float* __restrict__ topk_gate,
                          float* __restrict__ out){
  int i = blockIdx.x * 256 + threadIdx.x;
  int t = i >> 8;
  int c4 = (i & 255) * 4;
  int s0 = slot_of[2 * t], s1 = slot_of[2 * t + 1];
  float g0 = topk_gate[2 * t], g1 = topk_gate[2 * t + 1];
  float4 a0 = *(const float4*)(ya + (size_t)s0 * DD + c4);
  float4 b0 = *(const float4*)(yb + (size_t)s0 * DD + c4);
  float4 a1 = *(const float4*)(ya + (size_t)s1 * DD + c4);
  float4 b1 = *(const float4*)(yb + (size_t)s1 * DD + c4);
  float4 o;
  o.x = g0 * (a0.x + b0.x) + g1 * (a1.x + b1.x);
  o.y = g0 * (a0.y + b0.y) + g1 * (a1.y + b1.y);
  o.z = g0 * (a0.z + b0.z) + g1 * (a1.z + b1.z);
  o.w = g0 * (a0.w + b0.w) + g1 * (a1.w + b1.w);
  *(float4*)(out + (size_t)t * DD + c4) = o;
}

// ---------------- launch ----------------

extern "C" void kernel_launch(void* const* d_in, const int* in_sizes, int n_in,
                              void* d_out, int out_size, void* d_ws, size_t ws_size,
                              hipStream_t stream){
  (void)in_sizes; (void)n_in; (void)out_size; (void)ws_size;
  const float* x  = (const float*)d_in[0];
  const float* Wg = (const float*)d_in[1];
  const float* W1 = (const float*)d_in[2];
  const float* b1 = (const float*)d_in[3];
  const float* W2 = (const float*)d_in[4];
  const float* b2 = (const float*)d_in[5];
  float* out = (float*)d_out;
  char* ws = (char*)d_ws;

  int*   counts    = (int*)(ws + 0);
  int*   poff      = (int*)(ws + 256);
  int*   topk_idx  = (int*)(ws + 1024);
  float* topk_gate = (float*)(ws + 33792);
  int*   row_token = (int*)(ws + 66560);
  float* row_gate  = (float*)(ws + 103424);
  int*   slot_of   = (int*)(ws + 140288);
  short* xb        = (short*)(ws + 173056);
  short* w1t       = (short*)(ws + 8561664);
  short* w2t       = (short*)(ws + 75670528);
  short* h         = (short*)(ws + 142779392);
  float* ya        = (float*)(ws + 173056);
  float* yb        = (float*)(ws + 37921792);

  hipMemsetAsync(counts, 0, 32, stream);

  k_prep_w1t<<<dim3(1024 + 4096), 256, 0, stream>>>(x, Wg, xb, topk_idx, topk_gate,
                                                    counts, W1, w1t);
  k_route_all<<<dim3(1), 256, 0, stream>>>(counts, topk_idx, topk_gate, poff,
                                           row_token, row_gate, slot_of);
  k_gemm1_w2t<<<dim3(NG1 + 4096), 256, 0, stream>>>(xb, w1t, b1, h, row_token, poff,
                                                    W2, w2t);
  k_gemm2<<<dim3(ROWTILES * (DD / BN) * KP2), 256, 0, stream>>>(h, w2t, b2, ya, yb, poff);
  k_combine<<<dim3(NTOK * DD / 4 / 256), 256, 0, stream>>>(ya, yb, slot_of, topk_gate, out);
}